// Round 8
// baseline (423.492 us; speedup 1.0000x reference)
//
#include <hip/hip_runtime.h>
#include <hip/hip_bf16.h>

typedef unsigned int u32;
typedef float f32x4 __attribute__((ext_vector_type(4)));
typedef __bf16 bf16x8 __attribute__((ext_vector_type(8)));

#define BATCH 128
#define NIN   1024
#define DIN   256
#define NC    16
#define DC    32
#define NCOL  512   // NC*DC
#define JT    32    // j-tile rows
#define NCH   32    // chunks per batch (NIN/JT)
#define TPB   4     // tiles per block (grid-stride)

__device__ __forceinline__ float bflo(u32 v){ return __uint_as_float(v << 16); }
__device__ __forceinline__ float bfhi(u32 v){ return __uint_as_float(v & 0xffff0000u); }
__device__ __forceinline__ u32 bfround(u32 ua){ return (ua + 0x7fffu + ((ua >> 16) & 1u)) >> 16; }
__device__ __forceinline__ u32 pack2(float a, float b){
    return (bfround(__float_as_uint(a)) & 0xffffu) | (bfround(__float_as_uint(b)) << 16);
}
__device__ __forceinline__ bf16x8 ldfrag(const u32* p){
    return __builtin_bit_cast(bf16x8, *(const uint4*)p);
}
__device__ __forceinline__ int rot4(int n){ return (n + (n >> 3) + (n >> 5)) & 3; }

// K0: Wt2 = W in MFMA B-fragment order (verified round 5/7).
__global__ __launch_bounds__(256) void k_wconv(const float* __restrict__ W, uint4* __restrict__ Wt2){
    int id = blockIdx.x * 256 + threadIdx.x;       // 0..16383
    int l = id & 63, ks = (id >> 6) & 7, ntile = id >> 9;
    int n = ntile * 16 + (l & 15);
    int w0 = ks * 16 + (l >> 4) * 4;
    u32 r[4];
    #pragma unroll
    for (int e = 0; e < 4; e++){
        int w = w0 + e;
        r[e] = pack2(W[(size_t)(2 * w) * NCOL + n], W[(size_t)(2 * w + 1) * NCOL + n]);
    }
    Wt2[id] = make_uint4(r[0], r[1], r[2], r[3]);
}

// K1: u_hat = x@W, grid-stride (4 tiles/block) with double-buffered LDS x staging.
// uhat layout: word[((b*NCH + ch)*NCOL + n)*16 + jp]. Iter-0 col sums -> yp[ch][b][n].
__global__ __launch_bounds__(512) void k_gemm(const float* __restrict__ x, const uint4* __restrict__ Wt2,
                                              u32* __restrict__ uhat, float* __restrict__ yp){
    __shared__ __align__(16) u32 xl[2][JT * 128];   // 2 x 16 KB
    const int t = threadIdx.x, bid = blockIdx.x;
    const int lane = t & 63, wv = t >> 6;           // wave owns n in [wv*64, +64)
    const int l15 = lane & 15, q = lane >> 4;
    const int b = (bid * TPB) >> 5;                 // constant per block (TPB divides NCH)
    const int ch0 = (bid * TPB) & 31;
    const float4* xg = (const float4*)(x + (size_t)b * NIN * DIN);

    float4 pf[4];
    // prologue: load tile 0
    {
        int base = (ch0 * JT * DIN) >> 2;
        #pragma unroll
        for (int m = 0; m < 2; m++){
            pf[2*m]   = xg[base + 2 * (t + 512 * m)];
            pf[2*m+1] = xg[base + 2 * (t + 512 * m) + 1];
        }
        #pragma unroll
        for (int m = 0; m < 2; m++){
            int p = t + 512 * m;                     // uint4 id 0..1023
            int j = p >> 5, wq = 4 * (p & 31);
            uint4 v;
            v.x = pack2(pf[2*m].x, pf[2*m].y);   v.y = pack2(pf[2*m].z, pf[2*m].w);
            v.z = pack2(pf[2*m+1].x, pf[2*m+1].y); v.w = pack2(pf[2*m+1].z, pf[2*m+1].w);
            *(uint4*)&xl[0][j * 128 + ((wq + 4 * j) & 127)] = v;
        }
    }
    __syncthreads();

    for (int tl = 0; tl < TPB; tl++){
        const int ch = ch0 + tl, buf = tl & 1;
        // issue next tile's loads (overlap with compute)
        if (tl + 1 < TPB){
            int base = ((ch + 1) * JT * DIN) >> 2;
            #pragma unroll
            for (int m = 0; m < 2; m++){
                pf[2*m]   = xg[base + 2 * (t + 512 * m)];
                pf[2*m+1] = xg[base + 2 * (t + 512 * m) + 1];
            }
        }
        // K-loop
        f32x4 acc[2][4];
        #pragma unroll
        for (int mt = 0; mt < 2; mt++)
            #pragma unroll
            for (int nt = 0; nt < 4; nt++) acc[mt][nt] = (f32x4){0.f,0.f,0.f,0.f};
        uint4 bnx[4], bcr[4];
        #pragma unroll
        for (int nt = 0; nt < 4; nt++) bnx[nt] = Wt2[(size_t)(((wv*4+nt)*8) * 64) + lane];
        #pragma unroll
        for (int ks = 0; ks < 8; ks++){
            bf16x8 af[2];
            #pragma unroll
            for (int mt = 0; mt < 2; mt++){
                int jr = mt * 16 + l15;
                af[mt] = ldfrag(&xl[buf][jr * 128 + ((ks * 16 + q * 4 + 4 * jr) & 127)]);
            }
            #pragma unroll
            for (int nt = 0; nt < 4; nt++) bcr[nt] = bnx[nt];
            if (ks < 7){
                #pragma unroll
                for (int nt = 0; nt < 4; nt++)
                    bnx[nt] = Wt2[(size_t)(((wv*4+nt)*8 + ks + 1) * 64) + lane];
            }
            #pragma unroll
            for (int mt = 0; mt < 2; mt++)
                #pragma unroll
                for (int nt = 0; nt < 4; nt++)
                    acc[mt][nt] = __builtin_amdgcn_mfma_f32_16x16x32_bf16(af[mt], __builtin_bit_cast(bf16x8, bcr[nt]), acc[mt][nt], 0, 0, 0);
        }
        // iter-0 y partials: sum 32 j rows -> yp[ch][b][n]
        #pragma unroll
        for (int nt = 0; nt < 4; nt++){
            float v = 0.f;
            #pragma unroll
            for (int mt = 0; mt < 2; mt++)
                #pragma unroll
                for (int r = 0; r < 4; r++) v += acc[mt][nt][r];
            v += __shfl_xor(v, 16);
            v += __shfl_xor(v, 32);
            if (lane < 16)
                yp[((size_t)ch * BATCH + b) * NCOL + wv * 64 + nt * 16 + lane] = v;
        }
        // uhat stores: row n = 16 words; (mt,q) cover even jp
        u32* ub = uhat + ((size_t)(b * NCH + ch) * NCOL) * 16;
        #pragma unroll
        for (int nt = 0; nt < 4; nt++){
            int n = wv * 64 + nt * 16 + l15;
            #pragma unroll
            for (int mt = 0; mt < 2; mt++){
                uint2 v;
                v.x = pack2(acc[mt][nt][0], acc[mt][nt][1]);
                v.y = pack2(acc[mt][nt][2], acc[mt][nt][3]);
                *(uint2*)&ub[n * 16 + mt * 8 + q * 2] = v;
            }
        }
        // pack next tile into alternate buffer
        if (tl + 1 < TPB){
            #pragma unroll
            for (int m = 0; m < 2; m++){
                int p = t + 512 * m;
                int j = p >> 5, wq = 4 * (p & 31);
                uint4 v;
                v.x = pack2(pf[2*m].x, pf[2*m].y);   v.y = pack2(pf[2*m].z, pf[2*m].w);
                v.z = pack2(pf[2*m+1].x, pf[2*m+1].y); v.w = pack2(pf[2*m+1].z, pf[2*m+1].w);
                *(uint4*)&xl[buf ^ 1][j * 128 + ((wq + 4 * j) & 127)] = v;
            }
        }
        __syncthreads();
    }
}

// K2: routing pass, grid-stride (4 tiles/block) with double-buffered u-tile staging.
__global__ __launch_bounds__(256) void k_route(const u32* __restrict__ uhat, const float* __restrict__ og,
                                               float* __restrict__ yp){
    __shared__ __align__(16) u32 ul[2][NCOL * 16];  // 2 x 32 KB, rotated 64B rows
    __shared__ float ol[NCOL];
    __shared__ float bbc[NC * 33];
    const int t = threadIdx.x, bid = blockIdx.x;
    const int b = (bid * TPB) >> 5;                 // constant per block
    const int ch0 = (bid * TPB) & 31;

    ol[t] = og[b * NCOL + t];
    ol[t + 256] = og[b * NCOL + t + 256];

    uint4 pf[8];
    const uint4* ug = (const uint4*)(uhat + ((size_t)b * NCH) * NCOL * 16);
    // prologue: stage tile 0
    {
        #pragma unroll
        for (int m = 0; m < 8; m++) pf[m] = ug[(size_t)ch0 * 2048 + t + 256 * m];
        uint4* ul4 = (uint4*)ul[0];
        #pragma unroll
        for (int m = 0; m < 8; m++){
            int id = t + 256 * m;
            int n = id >> 2, s = id & 3;
            ul4[n * 4 + ((s + rot4(n)) & 3)] = pf[m];
        }
    }
    __syncthreads();

    for (int tl = 0; tl < TPB; tl++){
        const int ch = ch0 + tl, buf = tl & 1;
        if (tl + 1 < TPB){
            #pragma unroll
            for (int m = 0; m < 8; m++) pf[m] = ug[(size_t)(ch + 1) * 2048 + t + 256 * m];
        }
        // bb: thread (i = t>>4, jq = t&15) -> 2 j's, k-loop 32
        {
            int i = t >> 4, jq = t & 15;
            float oc[DC];
            #pragma unroll
            for (int e = 0; e < 8; e++) *(float4*)&oc[4 * e] = *(const float4*)&ol[i * DC + 4 * e];
            float a0 = 0.f, a1 = 0.f;
            #pragma unroll
            for (int k = 0; k < DC; k++){
                int n = i * DC + k;
                u32 v = ul[buf][n * 16 + ((jq + 4 * rot4(n)) & 15)];
                a0 += oc[k] * bflo(v);
                a1 += oc[k] * bfhi(v);
            }
            bbc[i * 33 + 2 * jq]     = a0;
            bbc[i * 33 + 2 * jq + 1] = a1;
        }
        __syncthreads();
        if (t < 32){
            float m = -1e30f;
            #pragma unroll
            for (int i = 0; i < NC; i++) m = fmaxf(m, bbc[i * 33 + t]);
            float s = 0.f;
            #pragma unroll
            for (int i = 0; i < NC; i++){ float e = __expf(bbc[i * 33 + t] - m); bbc[i * 33 + t] = e; s += e; }
            float inv = 1.f / s;
            #pragma unroll
            for (int i = 0; i < NC; i++) bbc[i * 33 + t] *= inv;
        }
        __syncthreads();
        // y: n = t, t+256; dot over 32 j; plain store
        #pragma unroll
        for (int h = 0; h < 2; h++){
            int n = t + 256 * h;
            int i = n >> 5;
            float cc[32];
            #pragma unroll
            for (int j = 0; j < 32; j++) cc[j] = bbc[i * 33 + j];
            float s = 0.f;
            const uint4* ul4 = (const uint4*)ul[buf];
            #pragma unroll
            for (int s4 = 0; s4 < 4; s4++){
                uint4 v = ul4[n * 4 + ((s4 + rot4(n)) & 3)];
                int j0 = s4 * 8;
                s += cc[j0+0] * bflo(v.x) + cc[j0+1] * bfhi(v.x)
                   + cc[j0+2] * bflo(v.y) + cc[j0+3] * bfhi(v.y)
                   + cc[j0+4] * bflo(v.z) + cc[j0+5] * bfhi(v.z)
                   + cc[j0+6] * bflo(v.w) + cc[j0+7] * bfhi(v.w);
            }
            yp[((size_t)ch * BATCH + b) * NCOL + n] = s;
        }
        if (tl + 1 < TPB){
            uint4* ul4 = (uint4*)ul[buf ^ 1];
            #pragma unroll
            for (int m = 0; m < 8; m++){
                int id = t + 256 * m;
                int n = id >> 2, s = id & 3;
                ul4[n * 4 + ((s + rot4(n)) & 3)] = pf[m];
            }
        }
        __syncthreads();
    }
}

// K3: y[n] = sum_p yp; o = squash; grid (4 n-groups x 128 b) x 128 thr
__global__ __launch_bounds__(128) void k_sz(const float* __restrict__ yp,
                                            float* __restrict__ og, float* __restrict__ out, int final){
    const int gx = blockIdx.x, b = blockIdx.y, t = threadIdx.x;
    const int n = gx * 128 + t;
    float s = 0.f;
    #pragma unroll 8
    for (int p = 0; p < NCH; p++) s += yp[((size_t)p * BATCH + b) * NCOL + n];
    float v = s * s;
    v += __shfl_xor(v, 1); v += __shfl_xor(v, 2); v += __shfl_xor(v, 4);
    v += __shfl_xor(v, 8); v += __shfl_xor(v, 16);
    float o = s / sqrtf(v + 1e-7f);
    og[b * NCOL + n] = o;
    if (final) out[(size_t)b * NCOL + n] = o;
}

extern "C" void kernel_launch(void* const* d_in, const int* in_sizes, int n_in,
                              void* d_out, int out_size, void* d_ws, size_t ws_size,
                              hipStream_t stream){
    const float* x = (const float*)d_in[0];    // fp32 [128][1024][256]
    const float* W = (const float*)d_in[1];    // fp32 [256][512]
    float* out = (float*)d_out;                // fp32 [128][16][32]
    float* f = (float*)d_ws;
    float* og   = f;                           // 65536 f
    float* ypr  = f + 65536;                   // 32*128*512 f (8 MB)
    uint4* Wt2  = (uint4*)(f + 65536 + 2097152);               // 256 KB
    u32*   uhat = (u32*)(f + 65536 + 2097152 + 65536);         // 134 MB

    k_wconv<<<64, 256, 0, stream>>>(W, Wt2);
    k_gemm<<<(BATCH * NCH) / TPB, 512, 0, stream>>>(x, Wt2, uhat, ypr);
    k_sz<<<dim3(4, BATCH), 128, 0, stream>>>(ypr, og, out, 0);
    for (int it = 1; it < 4; it++){
        k_route<<<(BATCH * NCH) / TPB, 256, 0, stream>>>(uhat, og, ypr);
        k_sz<<<dim3(4, BATCH), 128, 0, stream>>>(ypr, og, out, it == 3 ? 1 : 0);
    }
}